// Round 17
// baseline (467.995 us; speedup 1.0000x reference)
//
#include <hip/hip_runtime.h>

// out[b,o] = sum_h W2[o,h]*leaky(h) + b2[o],  h = W1[o]·x[b] + b1[o]
// leaky(t) = 0.6t + 0.4|t|
//   out[b,o] = 0.6(v[o]·x[b]) + c0[o] + sum_h (0.4 W2[o,h])|h|
// R18 = R17 (stage1 mfma16 K=16 exact, b1 rides f32-C; stage2 = 4 v_fma_f32
// with free |.| modifier; exact-f32 linear init; weights LDS-resident, no
// register arrays) with the ct-loop FULLY UNROLLED (R13's scheduling mode:
// static LDS offsets -> ds_read offset: immediates, compiler pipelines across
// iterations; R17's unroll-2 runtime base serialized lgkmcnt waits -> 32.9us
// vs R13 27.7us despite 40% more FLOPs in R13). Spill-safe: no register
// arrays (R14/R16 spills were register-array-caused, not unroll-caused).

#define H_DIM 512

typedef _Float16 f16x4 __attribute__((ext_vector_type(4)));
typedef __fp16   h16x2 __attribute__((ext_vector_type(2)));   // cvt_pkrtz native
typedef float    f32x4 __attribute__((ext_vector_type(4)));
typedef int      i32x2 __attribute__((ext_vector_type(2)));

// 512 blocks x 512 thr (8 waves), 2 blocks/CU (launch_bounds 2nd arg acts as
// blocks/CU: R13=(512,2)->cap128 verified, R15=(512,4)->cap64 verified).
// o = blk&15, grp = blk>>4 (32). Wave w: 8 tiles, tile0 = grp*64 + w*8.
__global__ __launch_bounds__(512, 2) void mlp_fused(
    const float* __restrict__ x, const float* __restrict__ W1,
    const float* __restrict__ b1, const float* __restrict__ W2,
    const float* __restrict__ b2, float* __restrict__ out) {
    __shared__ f16x4 sm_a1[2048];     // [ct][lane] W1 frags      16 KiB
    __shared__ f32x4 sm_w2c[128];     // [ct][kg] 0.4*W2           2 KiB
    __shared__ f32x4 sm_b1c[128];     // [ct][kg] b1               2 KiB
    __shared__ float red[512];
    __shared__ float v_sm[16];
    __shared__ float c_sm;

    const int tid = threadIdx.x;
    const int o   = blockIdx.x & 15;
    const int grp = blockIdx.x >> 4;
    const float* W1o = W1 + (size_t)o * H_DIM * 16;
    const float* W2o = W2 + (size_t)o * H_DIM;
    const float* b1o = b1 + (size_t)o * H_DIM;

    // ---- phase A: stage fragments ----
#pragma unroll
    for (int i = 0; i < 4; ++i) {
        const int e = tid + 512 * i;          // 0..2047 = [ct][lane]
        const int l = e & 63, ct = e >> 6;
        const int row = l & 15, kg = l >> 4;
        const f32x4 wv = *reinterpret_cast<const f32x4*>(
            W1o + (size_t)(ct * 16 + row) * 16 + kg * 4);
        h16x2 q0 = __builtin_amdgcn_cvt_pkrtz(wv[0], wv[1]);
        h16x2 q1 = __builtin_amdgcn_cvt_pkrtz(wv[2], wv[3]);
        i32x2 vi; vi[0] = __builtin_bit_cast(int, q0); vi[1] = __builtin_bit_cast(int, q1);
        sm_a1[e] = __builtin_bit_cast(f16x4, vi);
    }
    if (tid < 128) {                          // [ct][kg]
        const int kg = tid & 3, ct = tid >> 2;
        f32x4 wv, bv;
#pragma unroll
        for (int r = 0; r < 4; ++r) {
            wv[r] = 0.4f * W2o[ct * 16 + kg * 4 + r];
            bv[r] = b1o[ct * 16 + kg * 4 + r];
        }
        sm_w2c[tid] = wv;
        sm_b1c[tid] = bv;
    }
    {   // v[i] = 0.6 sum_h W2[h] W1[h,i]
        const int i = tid & 15, hc = tid >> 4;     // 32 chunks x 16 h
        float a = 0.f;
#pragma unroll
        for (int hh = 0; hh < 16; ++hh) {
            const int h = hc * 16 + hh;
            a = fmaf(W2o[h], W1o[(size_t)h * 16 + i], a);
        }
        red[tid] = a;
    }
    __syncthreads();
    if (tid < 16) {
        float s = 0.f;
#pragma unroll
        for (int k = 0; k < 32; ++k) s += red[tid + 16 * k];
        v_sm[tid] = 0.6f * s;
    }
    const float cp = W2o[tid] * b1o[tid];
    __syncthreads();
    red[tid] = cp;
    __syncthreads();
    if (tid < 64) {
        float s = 0.f;
#pragma unroll
        for (int k = 0; k < 8; ++k) s += red[tid + 64 * k];
#pragma unroll
        for (int m = 1; m <= 32; m <<= 1) s += __shfl_xor(s, m, 64);
        if (tid == 0) c_sm = 0.6f * s + b2[o];
    }
    __syncthreads();

    // ---- phase B ----
    const int lane = tid & 63, w = tid >> 6;
    const int col = lane & 15, kg = lane >> 4;
    const int tile0 = grp * 64 + w * 8;

    const f32x4 vr = *reinterpret_cast<const f32x4*>(&v_sm[kg * 4]);
    const float c0 = c_sm;

    // x load + exact-f32 linear init + f16 fold
    f16x4 xf[8];
    float nl[8];
#pragma unroll
    for (int j = 0; j < 8; ++j) {
        const f32x4 xv = *reinterpret_cast<const f32x4*>(
            x + (size_t)((tile0 + j) * 16 + col) * 16 + kg * 4);
        float lp = xv[0] * vr[0];
        lp = fmaf(xv[1], vr[1], lp);
        lp = fmaf(xv[2], vr[2], lp);
        lp = fmaf(xv[3], vr[3], lp);
        nl[j] = lp;
        h16x2 q0 = __builtin_amdgcn_cvt_pkrtz(xv[0], xv[1]);
        h16x2 q1 = __builtin_amdgcn_cvt_pkrtz(xv[2], xv[3]);
        i32x2 xi; xi[0] = __builtin_bit_cast(int, q0); xi[1] = __builtin_bit_cast(int, q1);
        xf[j] = __builtin_bit_cast(f16x4, xi);
    }

#pragma unroll
    for (int ct = 0; ct < 32; ++ct) {
        const f16x4 A1 = sm_a1[ct * 64 + lane];   // static offset: pipelined
        const f32x4 wv = sm_w2c[ct * 4 + kg];     // broadcast (kg-only addr)
        const f32x4 bv = sm_b1c[ct * 4 + kg];
#pragma unroll
        for (int j = 0; j < 8; ++j) {
            // stage1: d[r] = h[ct*16 + kg*4 + r] for b=col (bias via C)
            const f32x4 d = __builtin_amdgcn_mfma_f32_16x16x16f16(A1, xf[j], bv, 0, 0, 0);
            // stage2: 4 FMAs, |d| is a free VOP3 source modifier
            nl[j] = fmaf(wv[0], fabsf(d[0]), nl[j]);
            nl[j] = fmaf(wv[1], fabsf(d[1]), nl[j]);
            nl[j] = fmaf(wv[2], fabsf(d[2]), nl[j]);
            nl[j] = fmaf(wv[3], fabsf(d[3]), nl[j]);
        }
    }

    // reduce over kg (lanes differing in bits 4-5) and store
#pragma unroll
    for (int j = 0; j < 8; ++j) {
        float s = nl[j];
        s += __shfl_xor(s, 16, 64);
        s += __shfl_xor(s, 32, 64);
        if (lane < 16)
            out[(size_t)((tile0 + j) * 16 + lane) * 16 + o] = s + c0;
    }
}

extern "C" void kernel_launch(void* const* d_in, const int* in_sizes, int n_in,
                              void* d_out, int out_size, void* d_ws, size_t ws_size,
                              hipStream_t stream) {
    const float* x  = (const float*)d_in[0];
    const float* W1 = (const float*)d_in[1];
    const float* b1 = (const float*)d_in[2];
    const float* W2 = (const float*)d_in[3];
    const float* b2 = (const float*)d_in[4];
    float* out = (float*)d_out;

    mlp_fused<<<512, 512, 0, stream>>>(x, W1, b1, W2, b2, out);
}